// Round 1
// baseline (238.147 us; speedup 1.0000x reference)
//
#include <hip/hip_runtime.h>

// FixedActionDecoder: cosine-sim against 11 action words, segment-max to 4
// actions, argmax, one-hot. Row-norm of X is argmax-invariant -> skipped.

__global__ __launch_bounds__(256) void fixed_action_decoder(
    const float* __restrict__ X,   // [B, 64]
    const float* __restrict__ A,   // [64, 11] row-major (d*11 + p)
    float* __restrict__ out,       // [B, 4]
    int B)
{
    __shared__ float anorm[11][64];  // [p][d], each row 256 B (16B-aligned)

    const int tid = threadIdx.x;
    if (tid < 11) {
        // Normalize column tid of A (norm over d). Double for accuracy.
        double ss = 0.0;
        for (int d = 0; d < 64; ++d) {
            double v = (double)A[d * 11 + tid];
            ss += v * v;
        }
        double scale = 1.0 / fmax(sqrt(ss), 1e-8);
        for (int d = 0; d < 64; ++d) {
            anorm[tid][d] = (float)((double)A[d * 11 + tid] * scale);
        }
    }
    __syncthreads();

    const int l = tid & 15;   // lane within 16-lane row group
    const int g = tid >> 4;   // row group within block (0..15)
    const float4* X4 = reinterpret_cast<const float4*>(X);

    const int groups_per_grid = gridDim.x * 16;
    for (int r = blockIdx.x * 16 + g; r < B; r += groups_per_grid) {
        // 16 lanes x float4 = one 64-float row, fully coalesced across the wave.
        float4 v = X4[r * 16 + l];

        double s[11];
        #pragma unroll
        for (int p = 0; p < 11; ++p) {
            float4 a = reinterpret_cast<const float4*>(&anorm[p][0])[l];
            s[p] = (double)v.x * (double)a.x + (double)v.y * (double)a.y
                 + (double)v.z * (double)a.z + (double)v.w * (double)a.w;
        }

        // Butterfly reduce across the 16-lane group (stays inside group for
        // xor masks 1,2,4,8). All 16 lanes end with the full row dots.
        #pragma unroll
        for (int off = 1; off < 16; off <<= 1) {
            #pragma unroll
            for (int p = 0; p < 11; ++p)
                s[p] += __shfl_xor(s[p], off, 64);
        }

        // Segment max per ACTION_INDEX = [0,0,0,0, 1,1,1,1,1, 2, 3]
        double s0 = fmax(fmax(s[0], s[1]), fmax(s[2], s[3]));
        double s1 = fmax(fmax(fmax(s[4], s[5]), fmax(s[6], s[7])), s[8]);
        double s2 = s[9];
        double s3 = s[10];

        // argmax, first max wins (strict > like np.argmax)
        int idx = 0; double best = s0;
        if (s1 > best) { best = s1; idx = 1; }
        if (s2 > best) { best = s2; idx = 2; }
        if (s3 > best) { best = s3; idx = 3; }

        if (l < 4) out[r * 4 + l] = (l == idx) ? 1.0f : 0.0f;
    }
}

extern "C" void kernel_launch(void* const* d_in, const int* in_sizes, int n_in,
                              void* d_out, int out_size, void* d_ws, size_t ws_size,
                              hipStream_t stream) {
    const float* X = (const float*)d_in[0];
    const float* A = (const float*)d_in[1];
    float* out = (float*)d_out;
    const int B = in_sizes[0] / 64;

    int n_groups = (B + 15) / 16;
    int nblocks = n_groups < 2048 ? n_groups : 2048;
    hipLaunchKernelGGL(fixed_action_decoder, dim3(nblocks), dim3(256), 0, stream,
                       X, A, out, B);
}